// Round 4
// baseline (49.558 us; speedup 1.0000x reference)
//
#include <hip/hip_runtime.h>
#include <stdint.h>
#include <math.h>

#define NBOX 18
#define BB 512
#define DD 2048
#define NOBJ 16
#define KK 3
#define NCLS 174
#define NCAT 321
#define NQ 4
#define QCAND 2048  /* candidates per sampler block */
#define TINYF 1.1754943508222875e-38f

// ---------------- threefry2x32 (JAX-exact, 20 rounds) ----------------
__host__ __device__ __forceinline__ uint32_t rotl32(uint32_t x, int d) {
  return (x << d) | (x >> (32 - d));
}

__host__ __device__ __forceinline__ void threefry2x32(uint32_t k0, uint32_t k1,
                                                      uint32_t x0, uint32_t x1,
                                                      uint32_t& o0, uint32_t& o1) {
  uint32_t ks2 = k0 ^ k1 ^ 0x1BD11BDAu;
  x0 += k0; x1 += k1;
#define TFR(r) x0 += x1; x1 = rotl32(x1, r); x1 ^= x0;
#define R4A TFR(13) TFR(15) TFR(26) TFR(6)
#define R4B TFR(17) TFR(29) TFR(16) TFR(24)
  R4A x0 += k1;  x1 += ks2 + 1u;
  R4B x0 += ks2; x1 += k0 + 2u;
  R4A x0 += k0;  x1 += k1 + 3u;
  R4B x0 += k1;  x1 += ks2 + 4u;
  R4A x0 += ks2; x1 += k0 + 5u;
#undef R4A
#undef R4B
#undef TFR
  o0 = x0; o1 = x1;
}

__device__ __forceinline__ float bits_to_unit(uint32_t bits) {
  float f = __uint_as_float((bits >> 9) | 0x3f800000u);
  return f - 1.0f;
}

// ---------------- K1: sampler — 4 quarter-blocks per b ----------------
__global__ __launch_bounds__(256) void sample_kernel(
    const float* __restrict__ cooc, const int* __restrict__ obj_cat,
    const int* __restrict__ labels, uint32_t r1h, uint32_t r1l,
    unsigned long long* __restrict__ part, int* __restrict__ cnts) {
  const int gb = blockIdx.x;
  const int b = gb >> 2;
  const int q = gb & 3;
  const int tid = threadIdx.x;
  const int lane = tid & 63;
  const int wid = tid >> 6;  // 4 waves

  __shared__ unsigned short jl[QCAND];  // compacted candidate j, per-wave 512-stripes
  __shared__ float wl[QCAND];           // compacted w
  __shared__ float pv[KK * 4];
  __shared__ int pj[KK * 4];
  __shared__ int wc[4];

  const int lab = labels[b];
  const float* crow = cooc + (size_t)lab * NCAT;
  const int seg = wid << 9;              // wave's LDS stripe base (512)
  const int jbase = (q << 11) + seg;     // wave's candidate stripe base

  // ordered per-wave compaction (ballot+popcount, j-ascending preserved)
  int cnt = 0;
#pragma unroll 1
  for (int c = 0; c < 8; ++c) {
    int j = jbase + (c << 6) + lane;
    int jb = j >> 4;
    float w = 0.0f;
    if (jb != b) w = crow[obj_cat[jb * NBOX + 2 + (j & 15)]];
    unsigned long long m = __ballot(w > 0.0f);
    if (w > 0.0f) {
      int rank = __popcll(m & ((1ull << lane) - 1ull));
      jl[seg + cnt + rank] = (unsigned short)j;
      wl[seg + cnt + rank] = w;
    }
    cnt += __popcll(m);
  }
  if (lane == 0) wc[wid] = cnt;

  // 3 exponential races: argmax(g + log w) == argmax(w / -log u)
#pragma unroll 1
  for (int k = 0; k < KK; ++k) {
    uint32_t cbase = ((uint32_t)(k * BB + b)) << 13;
    float br = 0.0f;  // ratios strictly positive; 0 == "none"
    int bj = 0;
    for (int p = lane; p < cnt; p += 64) {
      uint32_t j = jl[seg + p];
      float w = wl[seg + p];
      uint32_t a0, a1;
      threefry2x32(r1h, r1l, 0u, cbase + j, a0, a1);
      float u = bits_to_unit(a0 ^ a1);
      if (u == 0.0f) u = TINYF;
      float t = -logf(u);
      if (w > br * t) { br = w / t; bj = (int)j; }  // strict >: first-index kept
    }
#pragma unroll
    for (int mm = 1; mm < 64; mm <<= 1) {
      float ov = __shfl_xor(br, mm, 64);
      int oj = __shfl_xor(bj, mm, 64);
      if (ov > br || (ov == br && oj < bj)) { br = ov; bj = oj; }
    }
    if (lane == 0) { pv[k * 4 + wid] = br; pj[k * 4 + wid] = bj; }
  }
  __syncthreads();

  if (tid == 0) {
    cnts[gb] = wc[0] + wc[1] + wc[2] + wc[3];
#pragma unroll
    for (int k = 0; k < KK; ++k) {
      float bv = pv[k * 4]; int bj = pj[k * 4];
      for (int w4 = 1; w4 < 4; ++w4) {
        float vv = pv[k * 4 + w4]; int jj = pj[k * 4 + w4];
        if (vv > bv || (vv == bv && jj < bj)) { bv = vv; bj = jj; }
      }
      // packed partial: high=ratio bits (monotone, >=0), low=8192-j (tie -> min j)
      part[((size_t)b * KK + k) * NQ + q] =
          ((unsigned long long)__float_as_uint(bv) << 32) | (uint32_t)(8192 - bj);
    }
  }
}

// ---------------- K2: finisher — ori + combine + mix_fea + mix_label ----------------
__global__ __launch_bounds__(256) void finish_kernel(
    const float* __restrict__ obj_fea, const int* __restrict__ obj_ind,
    const int* __restrict__ labels,
    const unsigned long long* __restrict__ part, const int* __restrict__ cnts,
    uint32_t r2h, uint32_t r2l, uint32_t r3bh, uint32_t r3bl,
    float* __restrict__ ori, float* __restrict__ mixf, float* __restrict__ mixl) {
  const int bx = blockIdx.x;
  const int b = bx >> 1;
  const int h = bx & 1;
  const int tid = threadIdx.x;
  const int off = (h << 8) + tid;  // float4 column within a row (512 per row)

  const float4* fea4 = (const float4*)obj_fea;
  const size_t rbase = (size_t)b * NBOX * 512 + off;

  float4 v0 = fea4[rbase];
  float4 v1 = fea4[rbase + 512];
  float4 S = make_float4(v0.x + v1.x, v0.y + v1.y, v0.z + v1.z, v0.w + v1.w);
#pragma unroll
  for (int r = 2; r < NBOX; ++r) {
    float4 a = fea4[rbase + (size_t)r * 512];
    S.x += a.x; S.y += a.y; S.z += a.z; S.w += a.w;
  }
  {
    const float is = 1.0f / 18.0f;
    float4 o = make_float4(S.x * is, S.y * is, S.z * is, S.w * is);
    ((float4*)ori)[(size_t)b * 512 + off] = o;
  }
  float4 S16 = make_float4(S.x - v0.x - v1.x, S.y - v0.y - v1.y,
                           S.z - v0.z - v1.z, S.w - v0.w - v1.w);

  __shared__ int s_sel[KK];
  __shared__ int s_slots[KK];
  __shared__ float s_lam;
  __shared__ int s_hc;
  if (tid < KK) {
    const int k = tid;
    unsigned long long best = part[((size_t)b * KK + k) * NQ];
#pragma unroll
    for (int q = 1; q < NQ; ++q) {
      unsigned long long p = part[((size_t)b * KK + k) * NQ + q];
      if (p > best) best = p;
    }
    s_sel[k] = 8192 - (int)(best & 0xFFFFFFFFull);
    uint32_t s0, s1;
    threefry2x32(r3bh, r3bl, 0u, (uint32_t)(b * KK + k), s0, s1);
    s_slots[k] = (int)((s0 ^ s1) & 15u);
  } else if (tid == 3) {
    int tot = cnts[b * NQ] + cnts[b * NQ + 1] + cnts[b * NQ + 2] + cnts[b * NQ + 3];
    int any = 0;
#pragma unroll
    for (int o = 0; o < NOBJ; ++o) any |= (obj_ind[b * NBOX + 2 + o] != 0);
    s_hc = (tot > 0) && any;
  } else if (tid == 4) {
    uint32_t c0, c1;
    threefry2x32(r2h, r2l, 0u, (uint32_t)b, c0, c1);
    s_lam = bits_to_unit(c0 ^ c1);
  }
  __syncthreads();

  const int hc = s_hc;
  const float l = s_lam, l1 = 1.0f - l;
  float4* mixf4 = (float4*)mixf;
  if (hc) {
#pragma unroll 1
    for (int k = 0; k < KK; ++k) {
      int s = s_sel[k];
      int bi = s >> 4, bo = s & 15, sl = s_slots[k];
      float4 a = fea4[((size_t)b * NBOX + 2 + sl) * 512 + off];
      float4 e = fea4[((size_t)bi * NBOX + 2 + bo) * 512 + off];
      float4 o;
      o.x = a.x * l + e.x * l1; o.y = a.y * l + e.y * l1;
      o.z = a.z * l + e.z * l1; o.w = a.w * l + e.w * l1;
      mixf4[((size_t)b * KK + k) * 512 + off] = o;
    }
  } else {
    const float is = 1.0f / 16.0f;
    float4 o = make_float4(S16.x * is, S16.y * is, S16.z * is, S16.w * is);
#pragma unroll
    for (int k = 0; k < KK; ++k) mixf4[((size_t)b * KK + k) * 512 + off] = o;
  }

  if (h == 0 && tid < NCLS) {
    int lb = labels[b];
#pragma unroll 1
    for (int k = 0; k < KK; ++k) {
      float val;
      if (hc) {
        int ls = labels[s_sel[k] >> 4];
        val = (tid == lb ? l : 0.0f) + (tid == ls ? l1 : 0.0f);
      } else {
        val = (tid == lb) ? 1.0f : 0.0f;
      }
      mixl[(size_t)(b * KK + k) * NCLS + tid] = val;
    }
  }
}

extern "C" void kernel_launch(void* const* d_in, const int* in_sizes, int n_in,
                              void* d_out, int out_size, void* d_ws, size_t ws_size,
                              hipStream_t stream) {
  (void)in_sizes; (void)n_in; (void)out_size; (void)ws_size;
  const float* obj_fea = (const float*)d_in[0];
  const float* cooc    = (const float*)d_in[1];
  const int* obj_ind   = (const int*)d_in[2];
  const int* obj_cat   = (const int*)d_in[3];
  const int* labels    = (const int*)d_in[4];

  float* out  = (float*)d_out;
  float* ori  = out;                              // 512*2048
  float* mixf = out + (size_t)BB * DD;            // 512*3*2048
  float* mixl = mixf + (size_t)BB * KK * DD;      // 512*3*174

  unsigned long long* part = (unsigned long long*)d_ws;  // 512*3*4 u64 = 48 KB
  int* cnts = (int*)((char*)d_ws + (size_t)BB * KK * NQ * 8);  // 512*4 int = 8 KB

  // key(42) -> split 3 (partitionable/fold-like): r_i = threefry(key,(0,i))
  uint32_t r1h, r1l, r2h, r2l, r3h, r3l;
  threefry2x32(0u, 42u, 0u, 0u, r1h, r1l);
  threefry2x32(0u, 42u, 0u, 1u, r2h, r2l);
  threefry2x32(0u, 42u, 0u, 2u, r3h, r3l);
  // randint(r3,...) splits internally: k1,k2 = split(r3); lower_bits uses k2
  uint32_t r3bh, r3bl;
  threefry2x32(r3h, r3l, 0u, 1u, r3bh, r3bl);

  hipLaunchKernelGGL(sample_kernel, dim3(BB * NQ), dim3(256), 0, stream,
                     cooc, obj_cat, labels, r1h, r1l, part, cnts);
  hipLaunchKernelGGL(finish_kernel, dim3(BB * 2), dim3(256), 0, stream,
                     obj_fea, obj_ind, labels, part, cnts,
                     r2h, r2l, r3bh, r3bl, ori, mixf, mixl);
}

// Round 5
// 43.030 us; speedup vs baseline: 1.1517x; 1.1517x over previous
//
#include <hip/hip_runtime.h>
#include <stdint.h>
#include <math.h>

#define NBOX 18
#define BB 512
#define DD 2048
#define NOBJ 16
#define KK 3
#define NCLS 174
#define NCAT 321
#define NQ 4
#define QCAND 2048
#define TINYF 1.1754943508222875e-38f

// ---------------- threefry2x32 (JAX-exact, 20 rounds) ----------------
__host__ __device__ __forceinline__ uint32_t rotl32(uint32_t x, int d) {
  return (x << d) | (x >> (32 - d));
}

__host__ __device__ __forceinline__ void threefry2x32(uint32_t k0, uint32_t k1,
                                                      uint32_t x0, uint32_t x1,
                                                      uint32_t& o0, uint32_t& o1) {
  uint32_t ks2 = k0 ^ k1 ^ 0x1BD11BDAu;
  x0 += k0; x1 += k1;
#define TFR(r) x0 += x1; x1 = rotl32(x1, r); x1 ^= x0;
#define R4A TFR(13) TFR(15) TFR(26) TFR(6)
#define R4B TFR(17) TFR(29) TFR(16) TFR(24)
  R4A x0 += k1;  x1 += ks2 + 1u;
  R4B x0 += ks2; x1 += k0 + 2u;
  R4A x0 += k0;  x1 += k1 + 3u;
  R4B x0 += k1;  x1 += ks2 + 4u;
  R4A x0 += ks2; x1 += k0 + 5u;
#undef R4A
#undef R4B
#undef TFR
  o0 = x0; o1 = x1;
}

__device__ __forceinline__ float bits_to_unit(uint32_t bits) {
  float f = __uint_as_float((bits >> 9) | 0x3f800000u);
  return f - 1.0f;
}

// ---- Kernel A: sampler quarter + overlapped ori/S16 stream ----
// grid 2048 = (b, quarter q); 256 threads = 4 waves.
__global__ __launch_bounds__(256) void fused_sample_ori(
    const float* __restrict__ obj_fea, const float* __restrict__ cooc,
    const int* __restrict__ obj_cat, const int* __restrict__ labels,
    uint32_t r1h, uint32_t r1l,
    unsigned long long* __restrict__ part, int* __restrict__ cnts,
    float* __restrict__ ori, float4* __restrict__ s16ws) {
  const int gb = blockIdx.x;
  const int b = gb >> 2;
  const int q = gb & 3;
  const int tid = threadIdx.x;
  const int lane = tid & 63;
  const int wid = tid >> 6;

  __shared__ unsigned short jl[QCAND];  // 4 KB, per-wave 512-stripes
  __shared__ float wl[QCAND];           // 8 KB
  __shared__ float pv[KK * 4];
  __shared__ int pj[KK * 4];
  __shared__ int wc[4];
  __shared__ float4 xch[128];           // 2 KB half-combine buffer

  // ---- p1: per-wave ordered compaction (gathers run before the big stream)
  const int lab = labels[b];
  const float* crow = cooc + (size_t)lab * NCAT;
  const int seg = wid << 9;
  const int jbase = (q << 11) + seg;
  int cnt = 0;
#pragma unroll 1
  for (int c = 0; c < 8; ++c) {
    int j = jbase + (c << 6) + lane;
    int jb = j >> 4;
    float w = 0.0f;
    if (jb != b) w = crow[obj_cat[jb * NBOX + 2 + (j & 15)]];
    unsigned long long m = __ballot(w > 0.0f);
    if (w > 0.0f) {
      int rank = __popcll(m & ((1ull << lane) - 1ull));
      jl[seg + cnt + rank] = (unsigned short)j;
      wl[seg + cnt + rank] = w;
    }
    cnt += __popcll(m);
  }
  if (lane == 0) wc[wid] = cnt;

  // ---- p0 (issued here): 9 named float4 loads per thread; land during p2
  // thread halves: half=0 -> rows 0..8, half=1 -> rows 9..17; col = D-slice float4
  const int col = tid & 127;
  const int half = tid >> 7;
  const float4* fea4 = (const float4*)obj_fea;
  const size_t lbase = ((size_t)b * NBOX + half * 9) * 512 + (q << 7) + col;
  float4 a0 = fea4[lbase];
  float4 a1 = fea4[lbase + 512];
  float4 a2 = fea4[lbase + 2 * 512];
  float4 a3 = fea4[lbase + 3 * 512];
  float4 a4 = fea4[lbase + 4 * 512];
  float4 a5 = fea4[lbase + 5 * 512];
  float4 a6 = fea4[lbase + 6 * 512];
  float4 a7 = fea4[lbase + 7 * 512];
  float4 a8 = fea4[lbase + 8 * 512];
  __builtin_amdgcn_sched_barrier(0);  // pin load issue before the races

  // ---- p2: 3 exponential races: argmax(g + log w) == argmax(w / -log u)
#pragma unroll 1
  for (int k = 0; k < KK; ++k) {
    uint32_t cbase = ((uint32_t)(k * BB + b)) << 13;
    float br = 0.0f;
    int bj = 0;
    for (int p = lane; p < cnt; p += 64) {
      uint32_t j = jl[seg + p];
      float w = wl[seg + p];
      uint32_t t0, t1;
      threefry2x32(r1h, r1l, 0u, cbase + j, t0, t1);
      float u = bits_to_unit(t0 ^ t1);
      if (u == 0.0f) u = TINYF;
      float t = -logf(u);
      if (w > br * t) { br = w / t; bj = (int)j; }  // strict >: first-index kept
    }
#pragma unroll
    for (int mm = 1; mm < 64; mm <<= 1) {
      float ov = __shfl_xor(br, mm, 64);
      int oj = __shfl_xor(bj, mm, 64);
      if (ov > br || (ov == br && oj < bj)) { br = ov; bj = oj; }
    }
    if (lane == 0) { pv[k * 4 + wid] = br; pj[k * 4 + wid] = bj; }
  }
  __syncthreads();

  if (tid == 0) {
    cnts[gb] = wc[0] + wc[1] + wc[2] + wc[3];
#pragma unroll
    for (int k = 0; k < KK; ++k) {
      float bv = pv[k * 4]; int bj = pj[k * 4];
      for (int w4 = 1; w4 < 4; ++w4) {
        float vv = pv[k * 4 + w4]; int jj = pj[k * 4 + w4];
        if (vv > bv || (vv == bv && jj < bj)) { bv = vv; bj = jj; }
      }
      part[((size_t)b * KK + k) * NQ + q] =
          ((unsigned long long)__float_as_uint(bv) << 32) | (uint32_t)(8192 - bj);
    }
  }

  // ---- p3: consume the stream (vmcnt waits here), combine halves, write ori+S16
  float4 A;
  A.x = a0.x + a1.x + a2.x + a3.x + a4.x + a5.x + a6.x + a7.x + a8.x;
  A.y = a0.y + a1.y + a2.y + a3.y + a4.y + a5.y + a6.y + a7.y + a8.y;
  A.z = a0.z + a1.z + a2.z + a3.z + a4.z + a5.z + a6.z + a7.z + a8.z;
  A.w = a0.w + a1.w + a2.w + a3.w + a4.w + a5.w + a6.w + a7.w + a8.w;
  if (half) xch[col] = A;  // sum rows 9..17
  __syncthreads();
  if (!half) {
    float4 Bv = xch[col];
    float4 S = make_float4(A.x + Bv.x, A.y + Bv.y, A.z + Bv.z, A.w + Bv.w);
    const float is = 1.0f / 18.0f;
    const size_t oidx = (size_t)b * 512 + (q << 7) + col;
    ((float4*)ori)[oidx] = make_float4(S.x * is, S.y * is, S.z * is, S.w * is);
    // S16 = sum rows 2..17 = S - r0 - r1 (r0,r1 are a0,a1 of half 0)
    s16ws[oidx] = make_float4(S.x - a0.x - a1.x, S.y - a0.y - a1.y,
                              S.z - a0.z - a1.z, S.w - a0.w - a1.w);
  }
}

// ---- Kernel B: mix finisher ----
// grid 1024 = (b, D-half); 256 threads, 1 float4/thread.
__global__ __launch_bounds__(256) void mix_kernel(
    const float* __restrict__ obj_fea, const int* __restrict__ obj_ind,
    const int* __restrict__ labels,
    const unsigned long long* __restrict__ part, const int* __restrict__ cnts,
    const float4* __restrict__ s16ws,
    uint32_t r2h, uint32_t r2l, uint32_t r3bh, uint32_t r3bl,
    float* __restrict__ mixf, float* __restrict__ mixl) {
  const int bx = blockIdx.x;
  const int b = bx >> 1;
  const int h = bx & 1;
  const int tid = threadIdx.x;
  const int off = (h << 8) + tid;  // float4 col in [0,512)

  __shared__ int s_sel[KK];
  __shared__ int s_slots[KK];
  __shared__ float s_lam;
  __shared__ int s_hc;
  if (tid < KK) {
    const int k = tid;
    unsigned long long best = part[((size_t)b * KK + k) * NQ];
#pragma unroll
    for (int qq = 1; qq < NQ; ++qq) {
      unsigned long long p = part[((size_t)b * KK + k) * NQ + qq];
      if (p > best) best = p;
    }
    s_sel[k] = 8192 - (int)(best & 0xFFFFFFFFull);
    uint32_t s0, s1;
    threefry2x32(r3bh, r3bl, 0u, (uint32_t)(b * KK + k), s0, s1);
    s_slots[k] = (int)((s0 ^ s1) & 15u);
  } else if (tid == 3) {
    int tot = cnts[b * NQ] + cnts[b * NQ + 1] + cnts[b * NQ + 2] + cnts[b * NQ + 3];
    int any = 0;
#pragma unroll
    for (int o = 0; o < NOBJ; ++o) any |= (obj_ind[b * NBOX + 2 + o] != 0);
    s_hc = (tot > 0) && any;
  } else if (tid == 4) {
    uint32_t c0, c1;
    threefry2x32(r2h, r2l, 0u, (uint32_t)b, c0, c1);
    s_lam = bits_to_unit(c0 ^ c1);
  }
  __syncthreads();

  const int hc = s_hc;
  const float l = s_lam, l1 = 1.0f - l;
  const float4* fea4 = (const float4*)obj_fea;
  float4* mixf4 = (float4*)mixf;
  if (hc) {
#pragma unroll 1
    for (int k = 0; k < KK; ++k) {
      int s = s_sel[k];
      int bi = s >> 4, bo = s & 15, sl = s_slots[k];
      float4 a = fea4[((size_t)b * NBOX + 2 + sl) * 512 + off];
      float4 e = fea4[((size_t)bi * NBOX + 2 + bo) * 512 + off];
      float4 o;
      o.x = a.x * l + e.x * l1; o.y = a.y * l + e.y * l1;
      o.z = a.z * l + e.z * l1; o.w = a.w * l + e.w * l1;
      mixf4[((size_t)b * KK + k) * 512 + off] = o;
    }
  } else {
    float4 s16 = s16ws[(size_t)b * 512 + off];
    const float is = 1.0f / 16.0f;
    float4 o = make_float4(s16.x * is, s16.y * is, s16.z * is, s16.w * is);
#pragma unroll
    for (int k = 0; k < KK; ++k) mixf4[((size_t)b * KK + k) * 512 + off] = o;
  }

  if (h == 0 && tid < NCLS) {
    int lb = labels[b];
#pragma unroll 1
    for (int k = 0; k < KK; ++k) {
      float val;
      if (hc) {
        int ls = labels[s_sel[k] >> 4];
        val = (tid == lb ? l : 0.0f) + (tid == ls ? l1 : 0.0f);
      } else {
        val = (tid == lb) ? 1.0f : 0.0f;
      }
      mixl[(size_t)(b * KK + k) * NCLS + tid] = val;
    }
  }
}

extern "C" void kernel_launch(void* const* d_in, const int* in_sizes, int n_in,
                              void* d_out, int out_size, void* d_ws, size_t ws_size,
                              hipStream_t stream) {
  (void)in_sizes; (void)n_in; (void)out_size; (void)ws_size;
  const float* obj_fea = (const float*)d_in[0];
  const float* cooc    = (const float*)d_in[1];
  const int* obj_ind   = (const int*)d_in[2];
  const int* obj_cat   = (const int*)d_in[3];
  const int* labels    = (const int*)d_in[4];

  float* out  = (float*)d_out;
  float* ori  = out;                              // 512*2048
  float* mixf = out + (size_t)BB * DD;            // 512*3*2048
  float* mixl = mixf + (size_t)BB * KK * DD;      // 512*3*174

  char* ws = (char*)d_ws;
  unsigned long long* part = (unsigned long long*)ws;           // 48 KB
  int* cnts = (int*)(ws + (size_t)BB * KK * NQ * 8);            // 8 KB
  float4* s16ws = (float4*)(ws + 64 * 1024);                    // 4 MB

  // key(42) -> split 3 (partitionable/fold-like): r_i = threefry(key,(0,i))
  uint32_t r1h, r1l, r2h, r2l, r3h, r3l;
  threefry2x32(0u, 42u, 0u, 0u, r1h, r1l);
  threefry2x32(0u, 42u, 0u, 1u, r2h, r2l);
  threefry2x32(0u, 42u, 0u, 2u, r3h, r3l);
  // randint(r3,...) splits internally: k1,k2 = split(r3); lower_bits uses k2
  uint32_t r3bh, r3bl;
  threefry2x32(r3h, r3l, 0u, 1u, r3bh, r3bl);

  hipLaunchKernelGGL(fused_sample_ori, dim3(BB * NQ), dim3(256), 0, stream,
                     obj_fea, cooc, obj_cat, labels, r1h, r1l,
                     part, cnts, ori, s16ws);
  hipLaunchKernelGGL(mix_kernel, dim3(BB * 2), dim3(256), 0, stream,
                     obj_fea, obj_ind, labels, part, cnts, s16ws,
                     r2h, r2l, r3bh, r3bl, mixf, mixl);
}